// Round 14
// baseline (215.262 us; speedup 1.0000x reference)
//
#include <hip/hip_runtime.h>

#define D 128
#define EG 4096   // edges per hist/scatter block (391 blocks — keep CUs busy)
#define PADW 16   // row padding multiple (branch-free agg, int4 offset loads)
#define NPW 4     // nodes per wave in agg (CLT-smooths wave imbalance)

typedef _Float16 h8 __attribute__((ext_vector_type(8)));
typedef _Float16 h2 __attribute__((ext_vector_type(2)));
typedef float f4 __attribute__((ext_vector_type(4)));
typedef unsigned u4 __attribute__((ext_vector_type(4)));

// ---- CSR build via two-level LDS counting sort (no global atomics) ------

// blocks 0..G-1: per-group histogram over dst-buckets.
// blocks G..G+127: W1/W2 transpose + fp16 convert. block G+128: zero row.
__global__ __launch_bounds__(256) void histprep_k(const int* __restrict__ dst,
                                                  int* __restrict__ counts,
                                                  const float* __restrict__ W1,
                                                  const float* __restrict__ W2,
                                                  _Float16* __restrict__ WT1,
                                                  _Float16* __restrict__ WT2,
                                                  _Float16* __restrict__ Hh,
                                                  int E, int NB, int G, int N) {
  __shared__ int hist[512];
  int g = blockIdx.x, t = threadIdx.x;
  if (g >= G) {
    int pb = g - G;
    if (pb < 128) {
      const float* W = (pb < 64) ? W1 : W2;
      _Float16* WT = (pb < 64) ? WT1 : WT2;
      int idx = (pb & 63) * 256 + t;
      int k = idx >> 7, col = idx & 127;
      WT[col * D + k] = (_Float16)W[idx];
    } else if (t < 128) {
      Hh[(size_t)N * D + t] = (_Float16)0.f;
    }
    return;
  }
  for (int b = t; b < NB; b += 256) hist[b] = 0;
  __syncthreads();
  int e0 = g * EG;
#pragma unroll
  for (int it = 0; it < EG / 256; ++it) {
    int e = e0 + it * 256 + t;
    if (e < E) atomicAdd(&hist[dst[e] >> 8], 1);
  }
  __syncthreads();
  for (int b = t; b < NB; b += 256) counts[b * G + g] = hist[b];
}

__global__ __launch_bounds__(256) void bsum_k(const int* __restrict__ in,
                                              int* __restrict__ bsum, int M) {
  __shared__ int s[256];
  int t = threadIdx.x, i = blockIdx.x * 256 + t;
  s[t] = (i < M) ? in[i] : 0;
  __syncthreads();
  for (int off = 128; off > 0; off >>= 1) {
    if (t < off) s[t] += s[t + off];
    __syncthreads();
  }
  if (t == 0) bsum[blockIdx.x] = s[0];
}

// scanfin2: exclusive scan; each block derives its base from raw bsum.
__global__ __launch_bounds__(256) void scanfin2_k(const int* __restrict__ in,
                                                  const int* __restrict__ bsum,
                                                  int* __restrict__ outx, int M) {
  __shared__ int s[256];
  __shared__ int bsh;
  int b = blockIdx.x, t = threadIdx.x, i = b * 256 + t;
  int part = 0;
  for (int k = t; k < b; k += 256) part += bsum[k];
  s[t] = part;
  __syncthreads();
  for (int off = 128; off > 0; off >>= 1) {
    if (t < off) s[t] += s[t + off];
    __syncthreads();
  }
  if (t == 0) bsh = s[0];
  __syncthreads();
  int base = bsh;
  __syncthreads();
  int v0 = (i < M) ? in[i] : 0;
  s[t] = v0;
  __syncthreads();
  for (int off = 1; off < 256; off <<= 1) {
    int v = (t >= off) ? s[t - off] : 0;
    __syncthreads();
    s[t] += v;
    __syncthreads();
  }
  if (i < M) outx[i] = base + s[t] - v0;
}

__global__ __launch_bounds__(256) void scatter_k(const int* __restrict__ src,
                                                 const int* __restrict__ dst,
                                                 const int* __restrict__ cscan,
                                                 unsigned* __restrict__ tmp,
                                                 int E, int NB, int G) {
  __shared__ int hist[512];
  __shared__ int base[512];
  int g = blockIdx.x, t = threadIdx.x;
  for (int b = t; b < NB; b += 256) {
    hist[b] = 0;
    base[b] = cscan[b * G + g];
  }
  __syncthreads();
  int e0 = g * EG;
#pragma unroll
  for (int it = 0; it < EG / 256; ++it) {
    int e = e0 + it * 256 + t;
    if (e < E) {
      int d = dst[e];
      int b = d >> 8;
      int r = atomicAdd(&hist[b], 1);
      tmp[base[b] + r] = ((unsigned)(d & 255) << 20) | (unsigned)src[e];
    }
  }
}

// Phase 4: per-bucket count/scan/rank. Row layout: slot0 = SELF edge, then
// in-edges, padded to multiple of PADW=16 with dummy (zero-row) offsets.
// eoff stores BYTE offsets (src*256). Bucket arenas 16-aligned.
__global__ __launch_bounds__(256) void bucket_k(const unsigned* __restrict__ tmp,
                                                const int* __restrict__ cscan,
                                                float* __restrict__ nrm,
                                                int2* __restrict__ rs2,
                                                int* __restrict__ eoff,
                                                int N, int E, int NB, int G) {
  __shared__ int cnt[256];
  __shared__ int sc[256];
  __shared__ int cur[256];
  int b = blockIdx.x, t = threadIdx.x;
  int seg0 = cscan[b * G];
  int seg1 = (b == NB - 1) ? E : cscan[(b + 1) * G];
  int pbase = (seg0 + b * 4112 + 15) & ~15;  // 4112 = 256*16 pad budget + align
  cnt[t] = 0;
  __syncthreads();
  for (int i = seg0 + t; i < seg1; i += 256)
    atomicAdd(&cnt[tmp[i] >> 20], 1);
  __syncthreads();
  int node = b * 256 + t;
  int v0 = cnt[t];
  int pd = (node < N) ? ((v0 + 1 + PADW - 1) & ~(PADW - 1)) : 0;
  sc[t] = pd;
  __syncthreads();
  for (int off = 1; off < 256; off <<= 1) {
    int v = (t >= off) ? sc[t - off] : 0;
    __syncthreads();
    sc[t] += v;
    __syncthreads();
  }
  int ex = sc[t] - pd;
  int rbeg = pbase + ex;
  cur[t] = rbeg + 1;  // slot 0 reserved for self edge
  if (node < N) {
    rs2[node] = make_int2(rbeg, rbeg + pd);
    nrm[node] = rsqrtf((float)v0 + 1.0f);
    eoff[rbeg] = node * 256;  // self edge
    int dummy = N * 256;      // zero row
    for (int k = v0 + 1; k < pd; ++k) eoff[rbeg + k] = dummy;
  }
  __syncthreads();
  for (int i = seg0 + t; i < seg1; i += 256) {
    unsigned p = tmp[i];
    int r = atomicAdd(&cur[p >> 20], 1);
    eoff[r] = (int)((p & 0xFFFFF) << 8);  // src*256 byte offset
  }
}

// ---- MFMA GEMM + norm fuse: Hh = fp16((X @ W) * nrm[row]) ---------------
template <bool FP32IN>
__global__ __launch_bounds__(256) void gemm_k(const void* __restrict__ Xv,
                                              const _Float16* __restrict__ WT,
                                              const float* __restrict__ nrm,
                                              _Float16* __restrict__ Hh, int N) {
  __shared__ _Float16 Wl[D * 136];
  int tid = threadIdx.x;
#pragma unroll
  for (int it = 0; it < 8; ++it) {
    int idx = it * 256 + tid;
    int col = idx >> 4, kseg = idx & 15;
    *(h8*)&Wl[col * 136 + kseg * 8] = *(const h8*)&WT[col * D + kseg * 8];
  }
  __syncthreads();
  int wave = tid >> 6, lane = tid & 63;
  int lr = lane & 15, lk = lane >> 4;
#pragma unroll
  for (int tt = 0; tt < 2; ++tt) {
    int tile = blockIdx.x * 8 + wave * 2 + tt;
    int row0 = tile * 16;
    if (row0 >= N) break;
    int row = row0 + lr;
    int rowc = row < N ? row : N - 1;
    h8 a[4];
    if constexpr (FP32IN) {
      const float* X = (const float*)Xv;
#pragma unroll
      for (int ks = 0; ks < 4; ++ks) {
        f4 p = *(const f4*)&X[(size_t)rowc * D + ks * 32 + lk * 8];
        f4 q = *(const f4*)&X[(size_t)rowc * D + ks * 32 + lk * 8 + 4];
        h8 t;
        t[0] = (_Float16)p[0]; t[1] = (_Float16)p[1];
        t[2] = (_Float16)p[2]; t[3] = (_Float16)p[3];
        t[4] = (_Float16)q[0]; t[5] = (_Float16)q[1];
        t[6] = (_Float16)q[2]; t[7] = (_Float16)q[3];
        a[ks] = t;
      }
    } else {
      const _Float16* X = (const _Float16*)Xv;
#pragma unroll
      for (int ks = 0; ks < 4; ++ks)
        a[ks] = *(const h8*)&X[(size_t)rowc * D + ks * 32 + lk * 8];
    }
    f4 acc[8];
#pragma unroll
    for (int ct = 0; ct < 8; ++ct) acc[ct] = (f4){0.f, 0.f, 0.f, 0.f};
#pragma unroll
    for (int ct = 0; ct < 8; ++ct) {
#pragma unroll
      for (int ks = 0; ks < 4; ++ks) {
        h8 b = *(const h8*)&Wl[(ct * 16 + lr) * 136 + ks * 32 + lk * 8];
        acc[ct] = __builtin_amdgcn_mfma_f32_16x16x32_f16(a[ks], b, acc[ct], 0, 0, 0);
      }
    }
#pragma unroll
    for (int r = 0; r < 4; ++r) {
      int ro = row0 + lk * 4 + r;
      if (ro < N) {
        float sc = nrm[ro];
#pragma unroll
        for (int ct = 0; ct < 8; ++ct)
          Hh[(size_t)ro * D + ct * 16 + lr] = (_Float16)(acc[ct][r] * sc);
      }
    }
  }
}

// ---- Fused aggregate + bias + ReLU (self folded as edge slot 0) ---------
// One wave per NPW consecutive nodes (sequential) — CLT-smooths the
// per-node row-length variance that left 30% of wave slots idle at 1
// node/wave. 16-lane group reads one 256B fp16 row (h8/lane); PADW=16:
// one int4 offset load -> 4 independent gathers; next iter prefetched.
template <bool F16OUT>
__global__ __launch_bounds__(256) void agg_k(const _Float16* __restrict__ Hh,
                                             const float* __restrict__ nrm,
                                             const int2* __restrict__ rs2,
                                             const int* __restrict__ eoff,
                                             const float* __restrict__ bias,
                                             void* __restrict__ outv, int N) {
  int wave = threadIdx.x >> 6, lane = threadIdx.x & 63;
  int grp = lane >> 4, sub = lane & 15;
  unsigned soff = (unsigned)sub * 16u;
  const char* base = (const char*)Hh;
  const h2 ones = {(_Float16)1.f, (_Float16)1.f};
  int n0 = (blockIdx.x * 4 + wave) * NPW;
#pragma unroll 1
  for (int c = 0; c < NPW; ++c) {
    int n = n0 + c;
    if (n >= N) break;
    int2 se = rs2[n];
    float acc[8] = {};
    int i = se.x;
    u4 offs = __builtin_nontemporal_load((const u4*)&eoff[i + grp * 4]);
    while (true) {
      u4 v0 = *(const u4*)(base + offs[0] + soff);
      u4 v1 = *(const u4*)(base + offs[1] + soff);
      u4 v2 = *(const u4*)(base + offs[2] + soff);
      u4 v3 = *(const u4*)(base + offs[3] + soff);
      i += PADW;
      bool more = i < se.y;
      u4 offn;
      if (more) offn = __builtin_nontemporal_load((const u4*)&eoff[i + grp * 4]);
#pragma unroll
      for (int k = 0; k < 4; ++k) {
        unsigned lo01 = __builtin_amdgcn_perm(v1[k], v0[k], 0x05040100u);
        unsigned hi01 = __builtin_amdgcn_perm(v1[k], v0[k], 0x07060302u);
        unsigned lo23 = __builtin_amdgcn_perm(v3[k], v2[k], 0x05040100u);
        unsigned hi23 = __builtin_amdgcn_perm(v3[k], v2[k], 0x07060302u);
        acc[2 * k] = __builtin_amdgcn_fdot2(__builtin_bit_cast(h2, lo01), ones,
                                            acc[2 * k], false);
        acc[2 * k + 1] = __builtin_amdgcn_fdot2(__builtin_bit_cast(h2, hi01), ones,
                                                acc[2 * k + 1], false);
        acc[2 * k] = __builtin_amdgcn_fdot2(__builtin_bit_cast(h2, lo23), ones,
                                            acc[2 * k], false);
        acc[2 * k + 1] = __builtin_amdgcn_fdot2(__builtin_bit_cast(h2, hi23), ones,
                                                acc[2 * k + 1], false);
      }
      if (!more) break;
      offs = offn;
    }
#pragma unroll
    for (int j = 0; j < 8; ++j) acc[j] += __shfl_xor(acc[j], 16);
#pragma unroll
    for (int j = 0; j < 8; ++j) acc[j] += __shfl_xor(acc[j], 32);
    if (grp == 0) {
      int d0 = sub * 8;
      float nn = nrm[n];
      f4 bl = *(const f4*)&bias[d0];
      f4 bh = *(const f4*)&bias[d0 + 4];
      float o[8];
#pragma unroll
      for (int j = 0; j < 8; ++j) {
        float bj = (j < 4) ? bl[j] : bh[j - 4];
        o[j] = fmaxf(acc[j] * nn + bj, 0.f);
      }
      if constexpr (F16OUT) {
        _Float16* out = (_Float16*)outv;
        h8 ov;
#pragma unroll
        for (int j = 0; j < 8; ++j) ov[j] = (_Float16)o[j];
        __builtin_nontemporal_store(ov, (h8*)&out[(size_t)n * D + d0]);
      } else {
        float* out = (float*)outv;
        f4 lo = {o[0], o[1], o[2], o[3]};
        f4 hi = {o[4], o[5], o[6], o[7]};
        __builtin_nontemporal_store(lo, (f4*)&out[(size_t)n * D + d0]);
        __builtin_nontemporal_store(hi, (f4*)&out[(size_t)n * D + d0 + 4]);
      }
    }
  }
}

// ---- launch -------------------------------------------------------------

extern "C" void kernel_launch(void* const* d_in, const int* in_sizes, int n_in,
                              void* d_out, int out_size, void* d_ws, size_t ws_size,
                              hipStream_t stream) {
  const float* x  = (const float*)d_in[0];
  const int*   ei = (const int*)d_in[1];
  const float* W1 = (const float*)d_in[2];
  const float* b1 = (const float*)d_in[3];
  const float* W2 = (const float*)d_in[4];
  const float* b2 = (const float*)d_in[5];
  float* out = (float*)d_out;

  int N = in_sizes[0] / D;   // 100000
  int E = in_sizes[1] / 2;   // 1600000
  const int* srcp = ei;
  const int* dstp = ei + E;

  int NB = (N + 255) / 256;        // 391 dst-buckets
  int G  = (E + EG - 1) / EG;      // 391 edge groups
  int M  = NB * G;                 // 152881
  int nbM = (M + 255) / 256;       // 598

  char* ws = (char*)d_ws;
  size_t off = 0;
  auto alloc = [&](size_t bytes) -> char* {
    char* p = ws + off;
    off = (off + bytes + 511) & ~(size_t)511;
    return p;
  };
  _Float16* Hh   = (_Float16*)alloc((size_t)(N + 1) * D * 2);  // +1 zero row
  _Float16* O1h  = (_Float16*)alloc((size_t)N * D * 2);
  float* normv     = (float*)alloc((size_t)N * 4);
  int2*  rs2       = (int2*)alloc((size_t)N * 8);
  int*   counts    = (int*)alloc((size_t)M * 4);
  int*   cscan     = (int*)alloc((size_t)M * 4);
  unsigned* tmp    = (unsigned*)alloc((size_t)E * 4);
  int*   eoff      = (int*)alloc((size_t)(E + (size_t)NB * 4112 + 64) * 4);
  int*   bsum      = (int*)alloc(4096);
  _Float16* WT1    = (_Float16*)alloc((size_t)D * D * 2);
  _Float16* WT2    = (_Float16*)alloc((size_t)D * D * 2);

  int tiles = (N + 15) / 16;
  int nbGemm = (tiles + 7) / 8;
  int nbAgg = (N + 4 * NPW - 1) / (4 * NPW);  // 4 waves x NPW nodes per block

  // CSR build (no global atomics); blocks G.. also do W-prep + zero row
  histprep_k<<<G + 129, 256, 0, stream>>>(dstp, counts, W1, W2, WT1, WT2, Hh,
                                          E, NB, G, N);
  bsum_k<<<nbM, 256, 0, stream>>>(counts, bsum, M);
  scanfin2_k<<<nbM, 256, 0, stream>>>(counts, bsum, cscan, M);
  scatter_k<<<G, 256, 0, stream>>>(srcp, dstp, cscan, tmp, E, NB, G);
  bucket_k<<<NB, 256, 0, stream>>>(tmp, cscan, normv, rs2, eoff, N, E, NB, G);

  // Layer 1
  gemm_k<true><<<nbGemm, 256, 0, stream>>>(x, WT1, normv, Hh, N);
  agg_k<true><<<nbAgg, 256, 0, stream>>>(Hh, normv, rs2, eoff, b1, O1h, N);
  // Layer 2
  gemm_k<false><<<nbGemm, 256, 0, stream>>>(O1h, WT2, normv, Hh, N);
  agg_k<false><<<nbAgg, 256, 0, stream>>>(Hh, normv, rs2, eoff, b2, out, N);
}

// Round 15
// 210.280 us; speedup vs baseline: 1.0237x; 1.0237x over previous
//
#include <hip/hip_runtime.h>

#define D 128
#define EG 4096   // edges per hist/scatter block (391 blocks — keep CUs busy)
#define PADW 16   // row padding multiple (branch-free agg, int4 offset loads)

typedef _Float16 h8 __attribute__((ext_vector_type(8)));
typedef _Float16 h2 __attribute__((ext_vector_type(2)));
typedef float f4 __attribute__((ext_vector_type(4)));
typedef unsigned u4 __attribute__((ext_vector_type(4)));

// ---- CSR build via two-level LDS counting sort (no global atomics) ------

// blocks 0..G-1: per-group histogram over dst-buckets.
// blocks G..G+127: W1/W2 transpose + fp16 convert. block G+128: zero row.
__global__ __launch_bounds__(256) void histprep_k(const int* __restrict__ dst,
                                                  int* __restrict__ counts,
                                                  const float* __restrict__ W1,
                                                  const float* __restrict__ W2,
                                                  _Float16* __restrict__ WT1,
                                                  _Float16* __restrict__ WT2,
                                                  _Float16* __restrict__ Hh,
                                                  int E, int NB, int G, int N) {
  __shared__ int hist[512];
  int g = blockIdx.x, t = threadIdx.x;
  if (g >= G) {
    int pb = g - G;
    if (pb < 128) {
      const float* W = (pb < 64) ? W1 : W2;
      _Float16* WT = (pb < 64) ? WT1 : WT2;
      int idx = (pb & 63) * 256 + t;
      int k = idx >> 7, col = idx & 127;
      WT[col * D + k] = (_Float16)W[idx];
    } else if (t < 128) {
      Hh[(size_t)N * D + t] = (_Float16)0.f;
    }
    return;
  }
  for (int b = t; b < NB; b += 256) hist[b] = 0;
  __syncthreads();
  int e0 = g * EG;
#pragma unroll
  for (int it = 0; it < EG / 256; ++it) {
    int e = e0 + it * 256 + t;
    if (e < E) atomicAdd(&hist[dst[e] >> 8], 1);
  }
  __syncthreads();
  for (int b = t; b < NB; b += 256) counts[b * G + g] = hist[b];
}

__global__ __launch_bounds__(256) void bsum_k(const int* __restrict__ in,
                                              int* __restrict__ bsum, int M) {
  __shared__ int s[256];
  int t = threadIdx.x, i = blockIdx.x * 256 + t;
  s[t] = (i < M) ? in[i] : 0;
  __syncthreads();
  for (int off = 128; off > 0; off >>= 1) {
    if (t < off) s[t] += s[t + off];
    __syncthreads();
  }
  if (t == 0) bsum[blockIdx.x] = s[0];
}

// scanfin2: exclusive scan; each block derives its base from raw bsum.
__global__ __launch_bounds__(256) void scanfin2_k(const int* __restrict__ in,
                                                  const int* __restrict__ bsum,
                                                  int* __restrict__ outx, int M) {
  __shared__ int s[256];
  __shared__ int bsh;
  int b = blockIdx.x, t = threadIdx.x, i = b * 256 + t;
  int part = 0;
  for (int k = t; k < b; k += 256) part += bsum[k];
  s[t] = part;
  __syncthreads();
  for (int off = 128; off > 0; off >>= 1) {
    if (t < off) s[t] += s[t + off];
    __syncthreads();
  }
  if (t == 0) bsh = s[0];
  __syncthreads();
  int base = bsh;
  __syncthreads();
  int v0 = (i < M) ? in[i] : 0;
  s[t] = v0;
  __syncthreads();
  for (int off = 1; off < 256; off <<= 1) {
    int v = (t >= off) ? s[t - off] : 0;
    __syncthreads();
    s[t] += v;
    __syncthreads();
  }
  if (i < M) outx[i] = base + s[t] - v0;
}

__global__ __launch_bounds__(256) void scatter_k(const int* __restrict__ src,
                                                 const int* __restrict__ dst,
                                                 const int* __restrict__ cscan,
                                                 unsigned* __restrict__ tmp,
                                                 int E, int NB, int G) {
  __shared__ int hist[512];
  __shared__ int base[512];
  int g = blockIdx.x, t = threadIdx.x;
  for (int b = t; b < NB; b += 256) {
    hist[b] = 0;
    base[b] = cscan[b * G + g];
  }
  __syncthreads();
  int e0 = g * EG;
#pragma unroll
  for (int it = 0; it < EG / 256; ++it) {
    int e = e0 + it * 256 + t;
    if (e < E) {
      int d = dst[e];
      int b = d >> 8;
      int r = atomicAdd(&hist[b], 1);
      tmp[base[b] + r] = ((unsigned)(d & 255) << 20) | (unsigned)src[e];
    }
  }
}

// Phase 4: per-bucket count/scan/rank. Row layout: slot0 = SELF edge, then
// in-edges, padded to multiple of PADW=16 with dummy (zero-row) offsets.
// eoff stores BYTE offsets (src*256). Bucket arenas 16-aligned.
__global__ __launch_bounds__(256) void bucket_k(const unsigned* __restrict__ tmp,
                                                const int* __restrict__ cscan,
                                                float* __restrict__ nrm,
                                                int2* __restrict__ rs2,
                                                int* __restrict__ eoff,
                                                int N, int E, int NB, int G) {
  __shared__ int cnt[256];
  __shared__ int sc[256];
  __shared__ int cur[256];
  int b = blockIdx.x, t = threadIdx.x;
  int seg0 = cscan[b * G];
  int seg1 = (b == NB - 1) ? E : cscan[(b + 1) * G];
  int pbase = (seg0 + b * 4112 + 15) & ~15;  // 4112 = 256*16 pad budget + align
  cnt[t] = 0;
  __syncthreads();
  for (int i = seg0 + t; i < seg1; i += 256)
    atomicAdd(&cnt[tmp[i] >> 20], 1);
  __syncthreads();
  int node = b * 256 + t;
  int v0 = cnt[t];
  int pd = (node < N) ? ((v0 + 1 + PADW - 1) & ~(PADW - 1)) : 0;
  sc[t] = pd;
  __syncthreads();
  for (int off = 1; off < 256; off <<= 1) {
    int v = (t >= off) ? sc[t - off] : 0;
    __syncthreads();
    sc[t] += v;
    __syncthreads();
  }
  int ex = sc[t] - pd;
  int rbeg = pbase + ex;
  cur[t] = rbeg + 1;  // slot 0 reserved for self edge
  if (node < N) {
    rs2[node] = make_int2(rbeg, rbeg + pd);
    nrm[node] = rsqrtf((float)v0 + 1.0f);
    eoff[rbeg] = node * 256;  // self edge
    int dummy = N * 256;      // zero row
    for (int k = v0 + 1; k < pd; ++k) eoff[rbeg + k] = dummy;
  }
  __syncthreads();
  for (int i = seg0 + t; i < seg1; i += 256) {
    unsigned p = tmp[i];
    int r = atomicAdd(&cur[p >> 20], 1);
    eoff[r] = (int)((p & 0xFFFFF) << 8);  // src*256 byte offset
  }
}

// ---- MFMA GEMM + norm fuse: Hh = fp16((X @ W) * nrm[row]) ---------------
template <bool FP32IN>
__global__ __launch_bounds__(256) void gemm_k(const void* __restrict__ Xv,
                                              const _Float16* __restrict__ WT,
                                              const float* __restrict__ nrm,
                                              _Float16* __restrict__ Hh, int N) {
  __shared__ _Float16 Wl[D * 136];
  int tid = threadIdx.x;
#pragma unroll
  for (int it = 0; it < 8; ++it) {
    int idx = it * 256 + tid;
    int col = idx >> 4, kseg = idx & 15;
    *(h8*)&Wl[col * 136 + kseg * 8] = *(const h8*)&WT[col * D + kseg * 8];
  }
  __syncthreads();
  int wave = tid >> 6, lane = tid & 63;
  int lr = lane & 15, lk = lane >> 4;
#pragma unroll
  for (int tt = 0; tt < 2; ++tt) {
    int tile = blockIdx.x * 8 + wave * 2 + tt;
    int row0 = tile * 16;
    if (row0 >= N) break;
    int row = row0 + lr;
    int rowc = row < N ? row : N - 1;
    h8 a[4];
    if constexpr (FP32IN) {
      const float* X = (const float*)Xv;
#pragma unroll
      for (int ks = 0; ks < 4; ++ks) {
        f4 p = *(const f4*)&X[(size_t)rowc * D + ks * 32 + lk * 8];
        f4 q = *(const f4*)&X[(size_t)rowc * D + ks * 32 + lk * 8 + 4];
        h8 t;
        t[0] = (_Float16)p[0]; t[1] = (_Float16)p[1];
        t[2] = (_Float16)p[2]; t[3] = (_Float16)p[3];
        t[4] = (_Float16)q[0]; t[5] = (_Float16)q[1];
        t[6] = (_Float16)q[2]; t[7] = (_Float16)q[3];
        a[ks] = t;
      }
    } else {
      const _Float16* X = (const _Float16*)Xv;
#pragma unroll
      for (int ks = 0; ks < 4; ++ks)
        a[ks] = *(const h8*)&X[(size_t)rowc * D + ks * 32 + lk * 8];
    }
    f4 acc[8];
#pragma unroll
    for (int ct = 0; ct < 8; ++ct) acc[ct] = (f4){0.f, 0.f, 0.f, 0.f};
#pragma unroll
    for (int ct = 0; ct < 8; ++ct) {
#pragma unroll
      for (int ks = 0; ks < 4; ++ks) {
        h8 b = *(const h8*)&Wl[(ct * 16 + lr) * 136 + ks * 32 + lk * 8];
        acc[ct] = __builtin_amdgcn_mfma_f32_16x16x32_f16(a[ks], b, acc[ct], 0, 0, 0);
      }
    }
#pragma unroll
    for (int r = 0; r < 4; ++r) {
      int ro = row0 + lk * 4 + r;
      if (ro < N) {
        float sc = nrm[ro];
#pragma unroll
        for (int ct = 0; ct < 8; ++ct)
          Hh[(size_t)ro * D + ct * 16 + lr] = (_Float16)(acc[ct][r] * sc);
      }
    }
  }
}

// ---- Fused aggregate + bias + ReLU (self folded as edge slot 0) ---------
// One wave per node; 16-lane group reads one 256B fp16 row (h8/lane).
// PADW=16: per group-iter one int4 offset load -> 4 independent gathers;
// next iteration's offsets prefetched (NT) before the VALU block.
template <bool F16OUT>
__global__ __launch_bounds__(256) void agg_k(const _Float16* __restrict__ Hh,
                                             const float* __restrict__ nrm,
                                             const int2* __restrict__ rs2,
                                             const int* __restrict__ eoff,
                                             const float* __restrict__ bias,
                                             void* __restrict__ outv, int N) {
  int wave = threadIdx.x >> 6, lane = threadIdx.x & 63;
  int n = blockIdx.x * 4 + wave;
  if (n >= N) return;
  int grp = lane >> 4, sub = lane & 15;
  unsigned soff = (unsigned)sub * 16u;
  int2 se = rs2[n];
  const char* base = (const char*)Hh;
  const h2 ones = {(_Float16)1.f, (_Float16)1.f};
  float acc[8] = {};
  int i = se.x;
  u4 offs = __builtin_nontemporal_load((const u4*)&eoff[i + grp * 4]);
  while (true) {
    u4 v0 = *(const u4*)(base + offs[0] + soff);
    u4 v1 = *(const u4*)(base + offs[1] + soff);
    u4 v2 = *(const u4*)(base + offs[2] + soff);
    u4 v3 = *(const u4*)(base + offs[3] + soff);
    i += PADW;
    bool more = i < se.y;
    u4 offn;
    if (more) offn = __builtin_nontemporal_load((const u4*)&eoff[i + grp * 4]);
#pragma unroll
    for (int k = 0; k < 4; ++k) {
      unsigned lo01 = __builtin_amdgcn_perm(v1[k], v0[k], 0x05040100u);
      unsigned hi01 = __builtin_amdgcn_perm(v1[k], v0[k], 0x07060302u);
      unsigned lo23 = __builtin_amdgcn_perm(v3[k], v2[k], 0x05040100u);
      unsigned hi23 = __builtin_amdgcn_perm(v3[k], v2[k], 0x07060302u);
      acc[2 * k] = __builtin_amdgcn_fdot2(__builtin_bit_cast(h2, lo01), ones,
                                          acc[2 * k], false);
      acc[2 * k + 1] = __builtin_amdgcn_fdot2(__builtin_bit_cast(h2, hi01), ones,
                                              acc[2 * k + 1], false);
      acc[2 * k] = __builtin_amdgcn_fdot2(__builtin_bit_cast(h2, lo23), ones,
                                          acc[2 * k], false);
      acc[2 * k + 1] = __builtin_amdgcn_fdot2(__builtin_bit_cast(h2, hi23), ones,
                                              acc[2 * k + 1], false);
    }
    if (!more) break;
    offs = offn;
  }
#pragma unroll
  for (int j = 0; j < 8; ++j) acc[j] += __shfl_xor(acc[j], 16);
#pragma unroll
  for (int j = 0; j < 8; ++j) acc[j] += __shfl_xor(acc[j], 32);
  if (grp == 0) {
    int d0 = sub * 8;
    float nn = nrm[n];
    f4 bl = *(const f4*)&bias[d0];
    f4 bh = *(const f4*)&bias[d0 + 4];
    float o[8];
#pragma unroll
    for (int j = 0; j < 8; ++j) {
      float bj = (j < 4) ? bl[j] : bh[j - 4];
      o[j] = fmaxf(acc[j] * nn + bj, 0.f);
    }
    if constexpr (F16OUT) {
      _Float16* out = (_Float16*)outv;
      h8 ov;
#pragma unroll
      for (int j = 0; j < 8; ++j) ov[j] = (_Float16)o[j];
      __builtin_nontemporal_store(ov, (h8*)&out[(size_t)n * D + d0]);
    } else {
      float* out = (float*)outv;
      f4 lo = {o[0], o[1], o[2], o[3]};
      f4 hi = {o[4], o[5], o[6], o[7]};
      __builtin_nontemporal_store(lo, (f4*)&out[(size_t)n * D + d0]);
      __builtin_nontemporal_store(hi, (f4*)&out[(size_t)n * D + d0 + 4]);
    }
  }
}

// ---- launch -------------------------------------------------------------

extern "C" void kernel_launch(void* const* d_in, const int* in_sizes, int n_in,
                              void* d_out, int out_size, void* d_ws, size_t ws_size,
                              hipStream_t stream) {
  const float* x  = (const float*)d_in[0];
  const int*   ei = (const int*)d_in[1];
  const float* W1 = (const float*)d_in[2];
  const float* b1 = (const float*)d_in[3];
  const float* W2 = (const float*)d_in[4];
  const float* b2 = (const float*)d_in[5];
  float* out = (float*)d_out;

  int N = in_sizes[0] / D;   // 100000
  int E = in_sizes[1] / 2;   // 1600000
  const int* srcp = ei;
  const int* dstp = ei + E;

  int NB = (N + 255) / 256;        // 391 dst-buckets
  int G  = (E + EG - 1) / EG;      // 391 edge groups
  int M  = NB * G;                 // 152881
  int nbM = (M + 255) / 256;       // 598

  char* ws = (char*)d_ws;
  size_t off = 0;
  auto alloc = [&](size_t bytes) -> char* {
    char* p = ws + off;
    off = (off + bytes + 511) & ~(size_t)511;
    return p;
  };
  _Float16* Hh   = (_Float16*)alloc((size_t)(N + 1) * D * 2);  // +1 zero row
  _Float16* O1h  = (_Float16*)alloc((size_t)N * D * 2);
  float* normv     = (float*)alloc((size_t)N * 4);
  int2*  rs2       = (int2*)alloc((size_t)N * 8);
  int*   counts    = (int*)alloc((size_t)M * 4);
  int*   cscan     = (int*)alloc((size_t)M * 4);
  unsigned* tmp    = (unsigned*)alloc((size_t)E * 4);
  int*   eoff      = (int*)alloc((size_t)(E + (size_t)NB * 4112 + 64) * 4);
  int*   bsum      = (int*)alloc(4096);
  _Float16* WT1    = (_Float16*)alloc((size_t)D * D * 2);
  _Float16* WT2    = (_Float16*)alloc((size_t)D * D * 2);

  int tiles = (N + 15) / 16;
  int nbGemm = (tiles + 7) / 8;
  int nbAgg = (N + 3) / 4;

  // CSR build (no global atomics); blocks G.. also do W-prep + zero row
  histprep_k<<<G + 129, 256, 0, stream>>>(dstp, counts, W1, W2, WT1, WT2, Hh,
                                          E, NB, G, N);
  bsum_k<<<nbM, 256, 0, stream>>>(counts, bsum, M);
  scanfin2_k<<<nbM, 256, 0, stream>>>(counts, bsum, cscan, M);
  scatter_k<<<G, 256, 0, stream>>>(srcp, dstp, cscan, tmp, E, NB, G);
  bucket_k<<<NB, 256, 0, stream>>>(tmp, cscan, normv, rs2, eoff, N, E, NB, G);

  // Layer 1
  gemm_k<true><<<nbGemm, 256, 0, stream>>>(x, WT1, normv, Hh, N);
  agg_k<true><<<nbAgg, 256, 0, stream>>>(Hh, normv, rs2, eoff, b1, O1h, N);
  // Layer 2
  gemm_k<false><<<nbGemm, 256, 0, stream>>>(O1h, WT2, normv, Hh, N);
  agg_k<false><<<nbAgg, 256, 0, stream>>>(Hh, normv, rs2, eoff, b2, out, N);
}